// Round 9
// baseline (275.165 us; speedup 1.0000x reference)
//
#include <hip/hip_runtime.h>

// WaveletParsingLayer: per-row stable stream compaction.
// x3[B,C,L] -> out[B,C,KEEP], dropping elements == FILLER (10.1f), order-preserving.
// x1, x2 are unused by the reference.
//
// R13: ledger: R4/R5 barrier value-stage 78-80us | R6 reg-pipeline 90us
// (spill) | R8 index+gather 89us | R9 ILP burst 78us | R12 zero-barrier
// 1-wave/row streaming ring 82us (VGPR44, FETCH/WRITE clean, occupancy 19%,
// VALU 9%). Convoy theory falsified: no barriers, same 80us plateau.
// Surviving explanation: CONCURRENCY CAP. Row-serial survivor offset forces
// 1 wave/row -> 2048 waves total = 8/CU; each wave idle ~95% of a ~3000
// cyc/chunk wall (VALU only ~140cyc/chunk). No structure at 2048 waves can
// fill 256 CUs against ~1-2k cycle memory latencies.
// Fix: break row-serialness with workspace counts (first d_ws use):
//   K1 count:   wave w of block b counts survivors in segment w (4096 elems)
//               of row b -> ws[b*4+w]. No LDS, no barriers, 32 waves/CU.
//   K2 compact: wave w re-reads segment w (L3-warm: 134MB < 256MB L3, just
//               touched by K1), computes base = excl. prefix of row's counts
//               (one int4 load), streams through a private 4KB LDS ring,
//               flushes 1KB quanta as 4 coalesced global_store_dword
//               (dword-granular: segment bases are unaligned).
//   8192 independent waves in K2 (4x more), zero barriers in both kernels.
// Ring safety: backlog<=255 + chunk<=256 = 511 in flight < 1024 capacity.
// Guard metrics: K2 WRITE_SIZE exactly 98304 KB; K2 FETCH small if L3-warm.

#define FILLER_VAL 10.1f
constexpr int L_LEN    = 16384;
constexpr int KEEP_LEN = 12288;
constexpr int SEGS     = 4;
constexpr int SEG_LEN  = L_LEN / SEGS;     // 4096 elements per segment
constexpr int WAVE     = 64;
constexpr int BLOCK    = 256;              // 4 waves; wave w <-> segment w
constexpr int CHUNK    = WAVE * 4;         // 256 elements per wave-chunk
constexpr int CPS      = SEG_LEN / CHUNK;  // 16 chunks per segment
constexpr int PF       = 8;                // prefetch depth (chunks in flight)
constexpr int RING     = 1024;             // floats per wave ring (4 KB)
constexpr int RM       = RING - 1;
constexpr int FQ       = 256;              // flush quantum (floats)

__device__ __forceinline__ int lane_prefix(unsigned long long m)
{
    // popcount(m & ((1<<lane)-1)) in 2 VALU ops.
    return __builtin_amdgcn_mbcnt_hi((unsigned)(m >> 32),
           __builtin_amdgcn_mbcnt_lo((unsigned)m, 0u));
}

// ---- K1: per-segment survivor counts. Pure streaming read, 32 waves/CU.
__global__ __launch_bounds__(BLOCK, 8) void count_kernel(
    const float* __restrict__ x3, int* __restrict__ cnt)
{
    const int row  = blockIdx.x;
    const int lane = threadIdx.x & 63;
    const int w    = threadIdx.x >> 6;
    const float* __restrict__ s = x3 + (size_t)row * L_LEN + w * SEG_LEN;

    int total = 0;                          // wave-uniform (ballot-derived)
    #pragma unroll 1
    for (int half = 0; half < CPS / PF; ++half) {
        float4 buf[PF];
        #pragma unroll
        for (int i = 0; i < PF; ++i)
            buf[i] = *reinterpret_cast<const float4*>(
                s + (half * PF + i) * CHUNK + lane * 4);
        #pragma unroll
        for (int i = 0; i < PF; ++i) {
            total += __popcll(__ballot(buf[i].x != FILLER_VAL))
                   + __popcll(__ballot(buf[i].y != FILLER_VAL))
                   + __popcll(__ballot(buf[i].z != FILLER_VAL))
                   + __popcll(__ballot(buf[i].w != FILLER_VAL));
        }
    }
    if (lane == 0) cnt[row * SEGS + w] = total;
}

// ---- K2: per-segment independent stream compaction (8192 waves).
__global__ __launch_bounds__(BLOCK, 6) void compact_kernel(
    const float* __restrict__ x3, const int* __restrict__ cnt,
    float* __restrict__ out)
{
    const int row  = blockIdx.x;
    const int lane = threadIdx.x & 63;
    const int w    = threadIdx.x >> 6;
    const float* __restrict__ s = x3 + (size_t)row * L_LEN + w * SEG_LEN;
    float* __restrict__ o = out + (size_t)row * KEEP_LEN;

    __shared__ float ring[SEGS][RING];      // 16 KB total; wave-private rings
    float* r = ring[w];

    // Exclusive prefix of this row's segment counts (wave-uniform).
    const int4 c4 = *reinterpret_cast<const int4*>(cnt + row * SEGS);
    int base = 0;
    if (w > 0) base += c4.x;
    if (w > 1) base += c4.y;
    if (w > 2) base += c4.z;

    // Prologue: fill prefetch pipeline.
    float4 buf[PF];
    #pragma unroll
    for (int i = 0; i < PF; ++i)
        buf[i] = *reinterpret_cast<const float4*>(s + i * CHUNK + lane * 4);

    int off = 0;   // wave-uniform: survivors produced (segment-local)
    int fl  = 0;   // wave-uniform: survivors flushed to global

    #pragma unroll 1
    for (int g = 0; g < CPS / PF; ++g) {
        #pragma unroll
        for (int sN = 0; sN < PF; ++sN) {   // sN compile-time -> buf[] static
            const int c = g * PF + sN;
            const float4 v = buf[sN];
            if (c + PF < CPS)
                buf[sN] = *reinterpret_cast<const float4*>(
                    s + (c + PF) * CHUNK + lane * 4);

            const bool kx = (v.x != FILLER_VAL);
            const bool ky = (v.y != FILLER_VAL);
            const bool kz = (v.z != FILLER_VAL);
            const bool kw = (v.w != FILLER_VAL);
            const unsigned long long m0 = __ballot(kx);
            const unsigned long long m1 = __ballot(ky);
            const unsigned long long m2 = __ballot(kz);
            const unsigned long long m3 = __ballot(kw);

            const int before = lane_prefix(m0) + lane_prefix(m1)
                             + lane_prefix(m2) + lane_prefix(m3);
            const int p0 = off + before;
            const int p1 = p0 + (int)kx;
            const int p2 = p1 + (int)ky;
            const int p3 = p2 + (int)kz;
            if (kx) r[p0 & RM] = v.x;
            if (ky) r[p1 & RM] = v.y;
            if (kz) r[p2 & RM] = v.z;
            if (kw) r[p3 & RM] = v.w;

            off += __popcll(m0) + __popcll(m1)
                 + __popcll(m2) + __popcll(m3);

            // Flush full quanta; dword-granular (segment base unaligned).
            while (off - fl >= FQ) {        // wave-uniform branch
                #pragma unroll
                for (int i = 0; i < FQ / WAVE; ++i) {
                    const int li = fl + i * WAVE + lane;
                    const float t = r[li & RM];
                    const int gp = base + li;
                    if (gp < KEEP_LEN) o[gp] = t;
                }
                fl += FQ;
            }
        }
    }

    // Tail: rem in [0, FQ).
    #pragma unroll
    for (int i = 0; i < FQ / WAVE; ++i) {
        const int li = fl + i * WAVE + lane;
        if (li < off) {
            const int gp = base + li;
            if (gp < KEEP_LEN) o[gp] = r[li & RM];
        }
    }
}

extern "C" void kernel_launch(void* const* d_in, const int* in_sizes, int n_in,
                              void* d_out, int out_size, void* d_ws, size_t ws_size,
                              hipStream_t stream)
{
    // in order: x1 [B,C,4096] f32 (unused), x2 [B,C,4096] f32 (unused),
    //           x3 [B,C,L] f32, keep_len (scalar int, value 12288)
    const float* x3 = (const float*)d_in[2];
    float* out = (float*)d_out;
    int* cnt = (int*)d_ws;                 // rows*SEGS ints = 32 KB of d_ws

    const int rows = in_sizes[2] / L_LEN;  // B*C = 2048

    count_kernel<<<rows, BLOCK, 0, stream>>>(x3, cnt);
    compact_kernel<<<rows, BLOCK, 0, stream>>>(x3, cnt, out);
}

// Round 10
// 257.965 us; speedup vs baseline: 1.0667x; 1.0667x over previous
//
#include <hip/hip_runtime.h>

// WaveletParsingLayer: per-row stable stream compaction.
// x3[B,C,L] -> out[B,C,KEEP], dropping elements == FILLER (10.1f), order-preserving.
// x1, x2 are unused by the reference.
//
// R14: ledger: R5 barrier-stage 79 | R9 ILP burst 78 | R12 zero-barrier ring
// 82 | R13 two-kernel 4x-waves ~100 combined (worse). Convoy, ILP, and
// concurrency-cap theories all falsified. Meanwhile the harness fill kernel
// hits 84% HBM peak at 9.6% occupancy -> low occupancy is NOT the barrier.
// Common to all ~80us variants: the LDS staging round-trip (scatter-addr
// chain -> ds_write -> ds_read -> store) + 48KB LDS capping residency at
// 3 blocks/CU. Untried: NO staging at all. Survivor positions within each
// wave-chunk are DENSE (consecutive output slots), so direct global stores
// touch <=8 lines per instruction in a ~1KB window; L2 merges to full lines
// (dense within row) -> HBM WRITE stays ~96MiB. Dropping the stage removes
// two phases, one barrier, all bank conflicts, and the LDS occupancy cap
// (only 256B wtot remains) -> ~6-7 blocks/CU at VGPR<=128.
// Guard metrics: WRITE_SIZE ~96-105MiB (partial-line inflation watch),
// OccupancyPercent 60-85. Falsifier: >=75us with high occupancy -> store
// issue path is the true wall.

#define FILLER_VAL 10.1f
constexpr int L_LEN    = 16384;
constexpr int KEEP_LEN = 12288;
constexpr int BLOCK    = 256;           // 4 waves of 64
constexpr int NW       = BLOCK / 64;    // waves per block = 4
constexpr int CHUNK    = BLOCK * 4;     // 1024 elements per chunk
constexpr int NC       = L_LEN / CHUNK; // 16 chunks per row

__global__ __launch_bounds__(BLOCK, 4) void compact_rows_kernel(
    const float* __restrict__ x3, float* __restrict__ out)
{
    const int row = blockIdx.x;
    const float* __restrict__ in = x3 + (size_t)row * L_LEN;
    float* __restrict__ o = out + (size_t)row * KEEP_LEN;

    const int tid  = threadIdx.x;
    const int lane = tid & 63;
    const int wid  = tid >> 6;
    const unsigned long long lt = (1ULL << lane) - 1ULL;

    __shared__ int wtot[NC][NW];        // 256 B — the only LDS use

    // ---- Phase A: load entire row (16 float4, one burst), ballots,
    //      pack per-chunk state (4 survivor bits | prefix<<4).
    float4 v[NC];
    #pragma unroll
    for (int c = 0; c < NC; ++c)
        v[c] = *reinterpret_cast<const float4*>(in + c * CHUNK + tid * 4);

    int pk[NC];
    #pragma unroll
    for (int c = 0; c < NC; ++c) {
        const unsigned long long m0 = __ballot(v[c].x != FILLER_VAL);
        const unsigned long long m1 = __ballot(v[c].y != FILLER_VAL);
        const unsigned long long m2 = __ballot(v[c].z != FILLER_VAL);
        const unsigned long long m3 = __ballot(v[c].w != FILLER_VAL);
        const int before = __popcll(m0 & lt) + __popcll(m1 & lt)
                         + __popcll(m2 & lt) + __popcll(m3 & lt);
        const int bits = (int)((m0 >> lane) & 1ULL)
                       | ((int)((m1 >> lane) & 1ULL) << 1)
                       | ((int)((m2 >> lane) & 1ULL) << 2)
                       | ((int)((m3 >> lane) & 1ULL) << 3);
        pk[c] = bits | (before << 4);
        if (lane == 0)
            wtot[c][wid] = __popcll(m0) + __popcll(m1)
                         + __popcll(m2) + __popcll(m3);
    }
    __syncthreads();   // the only barrier: wtot visible

    // ---- Phase B: prefix over (chunk, wave) + DIRECT dense global stores.
    // Positions within each wave-chunk are consecutive output slots, so each
    // store instruction's 64 addresses span <=1KB -> L2 merges to full lines.
    int run = 0;
    #pragma unroll
    for (int c = 0; c < NC; ++c) {
        int wb = run;
        #pragma unroll
        for (int w = 0; w < NW; ++w) {
            const int t = wtot[c][w];
            if (w < wid) wb += t;
            run += t;
        }
        const int bits   = pk[c] & 15;
        const int before = pk[c] >> 4;
        const int p0 = wb + before;
        const int p1 = p0 + (bits & 1);
        const int p2 = p1 + ((bits >> 1) & 1);
        const int p3 = p2 + ((bits >> 2) & 1);
        if ((bits & 1) && p0 < KEEP_LEN) o[p0] = v[c].x;
        if ((bits & 2) && p1 < KEEP_LEN) o[p1] = v[c].y;
        if ((bits & 4) && p2 < KEEP_LEN) o[p2] = v[c].z;
        if ((bits & 8) && p3 < KEEP_LEN) o[p3] = v[c].w;
    }
}

extern "C" void kernel_launch(void* const* d_in, const int* in_sizes, int n_in,
                              void* d_out, int out_size, void* d_ws, size_t ws_size,
                              hipStream_t stream)
{
    // in order: x1 [B,C,4096] f32 (unused), x2 [B,C,4096] f32 (unused),
    //           x3 [B,C,L] f32, keep_len (scalar int, value 12288)
    const float* x3 = (const float*)d_in[2];
    float* out = (float*)d_out;

    const int rows = in_sizes[2] / L_LEN;  // B*C = 2048

    compact_rows_kernel<<<rows, BLOCK, 0, stream>>>(x3, out);
}